// Round 8
// baseline (176.395 us; speedup 1.0000x reference)
//
#include <hip/hip_runtime.h>
#include <math.h>

typedef unsigned short u16;
typedef unsigned int   u32;
typedef __bf16 bf16x8 __attribute__((ext_vector_type(8)));
typedef float  f32x4  __attribute__((ext_vector_type(4)));

#define B_ROWS 16384
#define PC 16
#define EPS_SIM 1e-4f
#define LOG_MIN_F (-18.420680743952367f)
#define KL_IDX  (B_ROWS + B_ROWS * 512)   // 8404992
#define OR_IDX  (KL_IDX + 1)

// direct global->LDS async copy, 16B per lane (lds dest = uniform base + lane*16)
#define GLD16(gp, lp) __builtin_amdgcn_global_load_lds( \
    (const __attribute__((address_space(1))) void*)(gp), \
    (__attribute__((address_space(3))) void*)(lp), 16, 0, 0)

__device__ inline u16 f2bf(float f) {
    u32 u = __float_as_uint(f);
    return (u16)((u + 0x7FFFu + ((u >> 16) & 1u)) >> 16);
}
__device__ inline float bf2f(u16 h) { return __uint_as_float(((u32)h) << 16); }

// ---------------------------------------------------------------------------
// prep: ortho (block 0) + ALL input splits + pnorm + init, ONE launch
// ---------------------------------------------------------------------------
__device__ __forceinline__ void split4(const float* __restrict__ src,
                                       u16* __restrict__ hi, u16* __restrict__ lo,
                                       int i)
{
    float4 v = ((const float4*)src)[i];
    float f[4] = {v.x, v.y, v.z, v.w};
    u16 h[4], l[4];
#pragma unroll
    for (int k = 0; k < 4; ++k) {
        h[k] = f2bf(f[k]);
        l[k] = f2bf(f[k] - bf2f(h[k]));
    }
    ((ushort4*)hi)[i] = make_ushort4(h[0], h[1], h[2], h[3]);
    ((ushort4*)lo)[i] = make_ushort4(l[0], l[1], l[2], l[3]);
}

__global__ __launch_bounds__(256)
void prep_kernel(const float* __restrict__ x,   const float* __restrict__ W1,
                 const float* __restrict__ W2,  const float* __restrict__ Wd1,
                 const float* __restrict__ Wd2, const float* __restrict__ protos,
                 u16* __restrict__ x_h,  u16* __restrict__ x_l,
                 u16* __restrict__ W1h,  u16* __restrict__ W1l,
                 u16* __restrict__ W2h,  u16* __restrict__ W2l,
                 u16* __restrict__ Wd1h, u16* __restrict__ Wd1l,
                 u16* __restrict__ Wd2h, u16* __restrict__ Wd2l,
                 u16* __restrict__ ph,   u16* __restrict__ pl,
                 float* __restrict__ pnorm, float* __restrict__ S,
                 float* __restrict__ Mn, float* __restrict__ out)
{
    __shared__ float pk[PC][257];
    __shared__ float red[256];
    int blk = blockIdx.x, t = threadIdx.x;

    if (blk == 0) {
        // full ortho loss in one block (8 classes sequential); single writer
        float osum = 0.f;
        for (int c = 0; c < 8; ++c) {
            for (int i = t; i < PC * 256; i += 256)
                pk[i >> 8][i & 255] = protos[c * PC * 256 + i];
            __syncthreads();
            float mean = 0.f;
            for (int i = 0; i < PC; ++i) mean += pk[i][t];
            mean *= (1.f / (float)PC);
            for (int i = 0; i < PC; ++i) pk[i][t] -= mean;
            __syncthreads();
            int i = t >> 4, j = t & 15;
            float gg = 0.f;
            for (int l = 0; l < 256; ++l) gg += pk[i][l] * pk[j][l];
            gg -= (i == j) ? 1.f : 0.f;
            red[t] = gg * gg;
            __syncthreads();
            for (int s = 128; s; s >>= 1) { if (t < s) red[t] += red[t + s]; __syncthreads(); }
            if (t == 0) osum += sqrtf(red[0]);
            __syncthreads();
        }
        if (t == 0) out[OR_IDX] = osum * (1.f / 8.f);
        return;
    }
    int b2 = blk - 1;
    if (b2 < 8192)         split4(x,   x_h,  x_l,  b2 * 256 + t);
    else if (b2 < 8448)    split4(W1,  W1h,  W1l,  (b2 - 8192) * 256 + t);
    else if (b2 < 8704)    split4(W2,  W2h,  W2l,  (b2 - 8448) * 256 + t);
    else if (b2 < 8768)    split4(Wd1, Wd1h, Wd1l, (b2 - 8704) * 256 + t);
    else if (b2 < 8896)    split4(Wd2, Wd2h, Wd2l, (b2 - 8768) * 256 + t);
    else if (b2 < 8928)    split4(protos, ph, pl,  (b2 - 8896) * 256 + t);
    else if (b2 < 8930) {
        int tt = (b2 - 8928) * 256 + t;            // [0,512)
        int row = tt >> 2, q = tt & 3;
        const float* pr = protos + (size_t)row * 256 + q * 64;
        float s = 0.f;
#pragma unroll
        for (int j = 0; j < 16; ++j) {
            float4 v = *(const float4*)(pr + j * 4);
            s = fmaf(v.x, v.x, s); s = fmaf(v.y, v.y, s);
            s = fmaf(v.z, v.z, s); s = fmaf(v.w, v.w, s);
        }
        s += __shfl_xor(s, 1, 64);
        s += __shfl_xor(s, 2, 64);
        if (q == 0) pnorm[row] = s;
    } else {
        int i = (b2 - 8930) * 256 + t;             // [0,16384)
        S[i] = 0.f; Mn[i] = 0.f;
        if (i == 0) out[KL_IDX] = 0.f;
    }
}

// ---------------------------------------------------------------------------
// Split-bf16 MFMA GEMM, BM=64 x BN=128, BK=64, 4 waves, SINGLE 48KB LDS buf,
// two-barrier loop (round-6-proven): barrier -> ds_read all frags -> barrier
// -> stage(tk+1) -> 48 MFMAs.  8-chunk XOR swizzle (chunk+row)&7, <=2-way.
// MODE 0: relu -> split store
// MODE 3: tanh -> f32 store
// MODE 4: y<2 mu split store + |mu|^2 row-reduce; y>=2 logVar -> S row-reduce
// MODE 5: y<2 relu split store (dh); y==2 proto-distance epilogue + kl reduce
// ---------------------------------------------------------------------------
template<int MODE, int KK>
__global__ __launch_bounds__(256, 3)
void gemm_mfma(const u16* __restrict__ Ah_g, const u16* __restrict__ Al_g,
               const u16* __restrict__ Bh_g, const u16* __restrict__ Bl_g,
               const u16* __restrict__ Ph,   const u16* __restrict__ Pl,
               const float* __restrict__ bias,
               u16* __restrict__ Ch, u16* __restrict__ Cl,
               float* __restrict__ Cf,
               float* __restrict__ Srow, float* __restrict__ Mnorm,
               const int* __restrict__ tcls, const float* __restrict__ pnorm,
               const float* __restrict__ Wlast,
               float* __restrict__ out, float* __restrict__ kl_out,
               int ldc)
{
    __shared__ __align__(16) u16 LAh[64][64];
    __shared__ __align__(16) u16 LAl[64][64];
    __shared__ __align__(16) u16 LBh[128][64];
    __shared__ __align__(16) u16 LBl[128][64];
    __shared__ float klacc;

    const int t = threadIdx.x, lane = t & 63, wave = t >> 6;
    const int wm = wave >> 1, wn = wave & 1;
    const int bm = blockIdx.x * 64;
    const int y  = blockIdx.y;
    const bool proto = (MODE == 5) && (y == 2);
    const int bn = proto ? 0 : y * 128;
    const u16* Bh_p = proto ? Ph : Bh_g;
    const u16* Bl_p = proto ? Pl : Bl_g;
    const int rA = lane & 15, g = lane >> 4;
    const int wrow8 = lane >> 3, cp = lane & 7;   // staging: 8 rows x 8 chunks / GLD16

    if (t == 0) klacc = 0.f;

    f32x4 acc[2][4];
    const f32x4 z4 = {0.f, 0.f, 0.f, 0.f};
#pragma unroll
    for (int i = 0; i < 2; ++i)
#pragma unroll
        for (int j = 0; j < 4; ++j) acc[i][j] = z4;

    auto stage = [&](int kt) {   // 12 GLD16 per thread
#pragma unroll
        for (int s = 0; s < 2; ++s) {          // A: 2 slabs of 8 rows per wave
            int row = wave * 16 + s * 8 + wrow8;
            int c   = (cp - row) & 7;          // inverse swizzle on SOURCE
            size_t goff = (size_t)(bm + row) * KK + kt * 64 + c * 8;
            GLD16(Ah_g + goff, &LAh[wave * 16 + s * 8][0]);
            GLD16(Al_g + goff, &LAl[wave * 16 + s * 8][0]);
        }
#pragma unroll
        for (int s = 0; s < 4; ++s) {          // B: 4 slabs of 8 rows per wave
            int row = wave * 32 + s * 8 + wrow8;
            int c   = (cp - row) & 7;
            size_t goff = (size_t)(bn + row) * KK + kt * 64 + c * 8;
            GLD16(Bh_p + goff, &LBh[wave * 32 + s * 8][0]);
            GLD16(Bl_p + goff, &LBl[wave * 32 + s * 8][0]);
        }
    };

    constexpr int T = KK / 64;
    stage(0);
    for (int tk = 0; tk < T; ++tk) {
        __syncthreads();                 // vmcnt drained: tile tk in LDS

        bf16x8 aH[2][2], aL[2][2], bH[2][4], bL[2][4];   // [k-half][frag]
#pragma unroll
        for (int h = 0; h < 2; ++h) {
#pragma unroll
            for (int i = 0; i < 2; ++i) {
                int m = wm * 32 + i * 16 + rA;
                int c = ((h * 4 + g + m) & 7) * 8;        // swizzled READ
                aH[h][i] = *(const bf16x8*)&LAh[m][c];
                aL[h][i] = *(const bf16x8*)&LAl[m][c];
            }
#pragma unroll
            for (int j = 0; j < 4; ++j) {
                int n = wn * 64 + j * 16 + rA;
                int c = ((h * 4 + g + n) & 7) * 8;
                bH[h][j] = *(const bf16x8*)&LBh[n][c];
                bL[h][j] = *(const bf16x8*)&LBl[n][c];
            }
        }

        __syncthreads();                 // all reads done; safe to overwrite
        if (tk + 1 < T) stage(tk + 1);   // loads fly under the 48 MFMAs

#pragma unroll
        for (int h = 0; h < 2; ++h)
#pragma unroll
            for (int i = 0; i < 2; ++i)
#pragma unroll
                for (int j = 0; j < 4; ++j) {
                    acc[i][j] = __builtin_amdgcn_mfma_f32_16x16x32_bf16(aH[h][i], bH[h][j], acc[i][j], 0, 0, 0);
                    acc[i][j] = __builtin_amdgcn_mfma_f32_16x16x32_bf16(aL[h][i], bH[h][j], acc[i][j], 0, 0, 0);
                    acc[i][j] = __builtin_amdgcn_mfma_f32_16x16x32_bf16(aH[h][i], bL[h][j], acc[i][j], 0, 0, 0);
                }
    }

    if (proto) {
        // d^2 = |mu|^2 + |p|^2 - 2*cross for the class slab cols cls*16..+15
        float pn[4], wl[4];
#pragma unroll
        for (int j = 0; j < 4; ++j) {
            int col = wn * 64 + j * 16 + rA;
            pn[j] = pnorm[col];
            wl[j] = Wlast[col];
        }
#pragma unroll
        for (int i = 0; i < 2; ++i)
#pragma unroll
            for (int r = 0; r < 4; ++r) {
                int row = bm + wm * 32 + i * 16 + g * 4 + r;
                int cls = tcls[row];
                int jsel = cls & 3;
                bool owner = ((cls >> 2) == wn);
                float cv = 0.f, pnv = 0.f, wlv = 0.f;
#pragma unroll
                for (int j = 0; j < 4; ++j) {
                    bool sel = (j == jsel);
                    cv  = sel ? acc[i][j][r] : cv;
                    pnv = sel ? pn[j] : pnv;
                    wlv = sel ? wl[j] : wlv;
                }
                float dd  = fmaxf(Mnorm[row] + pnv - 2.f * cv, 0.f);
                float d   = sqrtf(dd);
                float sim = __logf((d + 1.0f) / (d + EPS_SIM));
                float kl  = Srow[row] + dd * (0.5f / 256.f);
                float klw = kl * sim;
                float num = klw;
                float den = (klw > 0.0f) ? sim : 0.0f;
                float ov  = sim * wlv;
                num += __shfl_xor(num, 1, 64); den += __shfl_xor(den, 1, 64); ov += __shfl_xor(ov, 1, 64);
                num += __shfl_xor(num, 2, 64); den += __shfl_xor(den, 2, 64); ov += __shfl_xor(ov, 2, 64);
                num += __shfl_xor(num, 4, 64); den += __shfl_xor(den, 4, 64); ov += __shfl_xor(ov, 4, 64);
                num += __shfl_xor(num, 8, 64); den += __shfl_xor(den, 8, 64); ov += __shfl_xor(ov, 8, 64);
                if (owner && rA == 0) {
                    out[row] = ov;
                    atomicAdd(&klacc, num / den);   // LDS atomic
                }
            }
        __syncthreads();
        if (t == 0) atomicAdd(kl_out, klacc * (1.f / (float)B_ROWS));
        return;
    }

    float bv[4];
#pragma unroll
    for (int j = 0; j < 4; ++j) bv[j] = bias[bn + wn * 64 + j * 16 + rA];

    if (MODE == 4 && y >= 2) {
        // logVar columns: S[row] += mean_l(0.5 e^lv - 0.5 lv - 0.5)
#pragma unroll
        for (int i = 0; i < 2; ++i)
#pragma unroll
            for (int r = 0; r < 4; ++r) {
                int row = bm + wm * 32 + i * 16 + g * 4 + r;
                float s = 0.f;
#pragma unroll
                for (int j = 0; j < 4; ++j) {
                    float lv = acc[i][j][r] + bv[j];
                    lv = fminf(fmaxf(lv, LOG_MIN_F), -LOG_MIN_F);
                    s += 0.5f * __expf(lv) - 0.5f * lv - 0.5f;
                }
                s += __shfl_xor(s, 1, 64); s += __shfl_xor(s, 2, 64);
                s += __shfl_xor(s, 4, 64); s += __shfl_xor(s, 8, 64);
                if (rA == 0) atomicAdd(&Srow[row], s * (1.f / 256.f));
            }
        return;
    }

#pragma unroll
    for (int i = 0; i < 2; ++i)
#pragma unroll
        for (int r = 0; r < 4; ++r) {
            size_t row = bm + wm * 32 + i * 16 + g * 4 + r;
            float sq = 0.f;
#pragma unroll
            for (int j = 0; j < 4; ++j) {
                int col = bn + wn * 64 + j * 16 + rA;
                float v = acc[i][j][r] + bv[j];
                if (MODE == 0 || MODE == 5) v = fmaxf(v, 0.f);
                if (MODE == 3) {
                    float e = __expf(2.f * v);
                    Cf[row * ldc + col] = 1.f - 2.f / (e + 1.f);
                } else {
                    u16 hh = f2bf(v);
                    u16 ll = f2bf(v - bf2f(hh));
                    Ch[row * ldc + col] = hh;
                    Cl[row * ldc + col] = ll;
                    if (MODE == 4) sq = fmaf(v, v, sq);
                }
            }
            if (MODE == 4) {   // |mu|^2 partial for this wave's 64 cols
                sq += __shfl_xor(sq, 1, 64); sq += __shfl_xor(sq, 2, 64);
                sq += __shfl_xor(sq, 4, 64); sq += __shfl_xor(sq, 8, 64);
                if (rA == 0) atomicAdd(&Mnorm[row], sq);
            }
        }
}

// ---------------------------------------------------------------------------
extern "C" void kernel_launch(void* const* d_in, const int* in_sizes, int n_in,
                              void* d_out, int out_size, void* d_ws, size_t ws_size,
                              hipStream_t stream)
{
    const float* x      = (const float*)d_in[0];
    const int*   tcls   = (const int*)  d_in[1];
    const float* protos = (const float*)d_in[2];
    const float* W1     = (const float*)d_in[3];
    const float* b1     = (const float*)d_in[4];
    const float* W2     = (const float*)d_in[5];
    const float* b2     = (const float*)d_in[6];
    const float* Wd1    = (const float*)d_in[7];
    const float* bd1    = (const float*)d_in[8];
    const float* Wd2    = (const float*)d_in[9];
    const float* bd2    = (const float*)d_in[10];
    const float* Wlast  = (const float*)d_in[11];

    float* out     = (float*)d_out;
    float* decoded = out + B_ROWS;

    // h (split bf16) lives in d_out's decoded region (33.55MB), overwritten by G4
    u16* h_h = (u16*)decoded;
    u16* h_l = h_h + 8388608;

    // workspace overlays: x region (32MB) reused for mu + dh after G1
    u16* wsu  = (u16*)d_ws;
    u16* x_h  = wsu;
    u16* x_l  = wsu + 8388608;
    u16* mu_h = wsu;
    u16* mu_l = wsu + 4194304;
    u16* dh_h = wsu + 8388608;
    u16* dh_l = wsu + 12582912;

    float* S     = (float*)((char*)d_ws + 33554432);
    float* klrow = S + 16384;                      // (unused now, kept for layout)
    u16* w = (u16*)(klrow + 16384);
    u16 *W1h = w, *W1l = w + 262144, *W2h = w + 524288, *W2l = w + 786432;
    u16 *Wd1h = w + 1048576, *Wd1l = w + 1114112, *Wd2h = w + 1179648, *Wd2l = w + 1310720;
    u16 *ph = w + 1441792, *pl = ph + 32768;       // protos split (128x256)
    float* munorm = (float*)(pl + 32768);          // 16384 f32
    float* pnorm  = munorm + 16384;                // 128 f32

    // ONE prep launch: ortho(blk0) + splits + pnorm + init
    hipLaunchKernelGGL(prep_kernel, dim3(8995), dim3(256), 0, stream,
                       x, W1, W2, Wd1, Wd2, protos,
                       x_h, x_l, W1h, W1l, W2h, W2l, Wd1h, Wd1l, Wd2h, Wd2l,
                       ph, pl, pnorm, S, munorm, out);

    // G1: h = relu(x @ W1^T + b1) -> split bf16
    hipLaunchKernelGGL((gemm_mfma<0, 512>), dim3(256, 4), dim3(256), 0, stream,
                       x_h, x_l, W1h, W1l, (u16*)nullptr, (u16*)nullptr, b1,
                       h_h, h_l, (float*)nullptr, (float*)nullptr, (float*)nullptr,
                       (int*)nullptr, (float*)nullptr, (float*)nullptr,
                       (float*)nullptr, (float*)nullptr, 512);
    // G2: conv = h @ W2^T + b2 -> mu split + munorm (y<2); S row-sums (y>=2)
    hipLaunchKernelGGL((gemm_mfma<4, 512>), dim3(256, 4), dim3(256), 0, stream,
                       h_h, h_l, W2h, W2l, (u16*)nullptr, (u16*)nullptr, b2,
                       mu_h, mu_l, (float*)nullptr, S, munorm,
                       (int*)nullptr, (float*)nullptr, (float*)nullptr,
                       (float*)nullptr, (float*)nullptr, 256);
    // G3': y<2: dh = relu(mu @ Wd1^T + bd1); y==2: proto distances + sim/kl/out
    hipLaunchKernelGGL((gemm_mfma<5, 256>), dim3(256, 3), dim3(256), 0, stream,
                       mu_h, mu_l, Wd1h, Wd1l, ph, pl, bd1,
                       dh_h, dh_l, (float*)nullptr, S, munorm,
                       tcls, pnorm, Wlast, out, out + KL_IDX, 256);
    // G4: decoded = tanh(dh @ Wd2^T + bd2) -> f32 (overwrites h region)
    hipLaunchKernelGGL((gemm_mfma<3, 256>), dim3(256, 4), dim3(256), 0, stream,
                       dh_h, dh_l, Wd2h, Wd2l, (u16*)nullptr, (u16*)nullptr, bd2,
                       (u16*)nullptr, (u16*)nullptr, decoded, (float*)nullptr, (float*)nullptr,
                       (int*)nullptr, (float*)nullptr, (float*)nullptr,
                       (float*)nullptr, (float*)nullptr, 512);
}

// Round 9
// 132.262 us; speedup vs baseline: 1.3337x; 1.3337x over previous
//
#include <hip/hip_runtime.h>
#include <math.h>

typedef unsigned short u16;
typedef unsigned int   u32;
typedef __bf16 bf16x8 __attribute__((ext_vector_type(8)));
typedef float  f32x4  __attribute__((ext_vector_type(4)));

#define B_ROWS 16384
#define PC 16
#define EPS_SIM 1e-4f
#define LOG_MIN_F (-18.420680743952367f)
#define KL_IDX  (B_ROWS + B_ROWS * 512)   // 8404992
#define OR_IDX  (KL_IDX + 1)

// direct global->LDS async copy, 16B per lane (lds dest = uniform base + lane*16)
#define GLD16(gp, lp) __builtin_amdgcn_global_load_lds( \
    (const __attribute__((address_space(1))) void*)(gp), \
    (__attribute__((address_space(3))) void*)(lp), 16, 0, 0)

__device__ inline u16 f2bf(float f) {
    u32 u = __float_as_uint(f);
    return (u16)((u + 0x7FFFu + ((u >> 16) & 1u)) >> 16);
}
__device__ inline float bf2f(u16 h) { return __uint_as_float(((u32)h) << 16); }

// ---------------------------------------------------------------------------
// prep: ALL input splits + pnorm + init in ONE launch (no LDS, pure streaming)
// ---------------------------------------------------------------------------
__device__ __forceinline__ void split4(const float* __restrict__ src,
                                       u16* __restrict__ hi, u16* __restrict__ lo,
                                       int i)
{
    float4 v = ((const float4*)src)[i];
    float f[4] = {v.x, v.y, v.z, v.w};
    u16 h[4], l[4];
#pragma unroll
    for (int k = 0; k < 4; ++k) {
        h[k] = f2bf(f[k]);
        l[k] = f2bf(f[k] - bf2f(h[k]));
    }
    ((ushort4*)hi)[i] = make_ushort4(h[0], h[1], h[2], h[3]);
    ((ushort4*)lo)[i] = make_ushort4(l[0], l[1], l[2], l[3]);
}

__global__ __launch_bounds__(256)
void prep_kernel(const float* __restrict__ x,   const float* __restrict__ W1,
                 const float* __restrict__ W2,  const float* __restrict__ Wd1,
                 const float* __restrict__ Wd2, const float* __restrict__ protos,
                 u16* __restrict__ x_h,  u16* __restrict__ x_l,
                 u16* __restrict__ W1h,  u16* __restrict__ W1l,
                 u16* __restrict__ W2h,  u16* __restrict__ W2l,
                 u16* __restrict__ Wd1h, u16* __restrict__ Wd1l,
                 u16* __restrict__ Wd2h, u16* __restrict__ Wd2l,
                 u16* __restrict__ ph,   u16* __restrict__ pl,
                 float* __restrict__ pnorm, float* __restrict__ S,
                 float* __restrict__ Mn, float* __restrict__ out)
{
    int blk = blockIdx.x, t = threadIdx.x;
    if (blk < 8192)        split4(x,   x_h,  x_l,  blk * 256 + t);
    else if (blk < 8448)   split4(W1,  W1h,  W1l,  (blk - 8192) * 256 + t);
    else if (blk < 8704)   split4(W2,  W2h,  W2l,  (blk - 8448) * 256 + t);
    else if (blk < 8768)   split4(Wd1, Wd1h, Wd1l, (blk - 8704) * 256 + t);
    else if (blk < 8896)   split4(Wd2, Wd2h, Wd2l, (blk - 8768) * 256 + t);
    else if (blk < 8928)   split4(protos, ph, pl,  (blk - 8896) * 256 + t);
    else if (blk < 8930) {
        int tt = (blk - 8928) * 256 + t;           // [0,512)
        int row = tt >> 2, q = tt & 3;
        const float* pr = protos + (size_t)row * 256 + q * 64;
        float s = 0.f;
#pragma unroll
        for (int j = 0; j < 16; ++j) {
            float4 v = *(const float4*)(pr + j * 4);
            s = fmaf(v.x, v.x, s); s = fmaf(v.y, v.y, s);
            s = fmaf(v.z, v.z, s); s = fmaf(v.w, v.w, s);
        }
        s += __shfl_xor(s, 1, 64);
        s += __shfl_xor(s, 2, 64);
        if (q == 0) pnorm[row] = s;
    } else {
        int i = (blk - 8930) * 256 + t;            // [0,16384)
        S[i] = 0.f; Mn[i] = 0.f;
        if (i == 0) { out[KL_IDX] = 0.f; out[OR_IDX] = 0.f; }
    }
}

// ---------------------------------------------------------------------------
// ortho loss: one block per class (8 parallel blocks), unrolled gram loop
// ---------------------------------------------------------------------------
__global__ __launch_bounds__(256)
void ortho_kernel(const float* __restrict__ protos, float* __restrict__ ortho_out)
{
    int c = blockIdx.x;
    __shared__ float pk[PC][257];
    __shared__ float red[256];
    int t = threadIdx.x;
    for (int i = t; i < PC * 256; i += 256)
        pk[i >> 8][i & 255] = protos[c * PC * 256 + i];
    __syncthreads();
    float mean = 0.0f;
#pragma unroll
    for (int i = 0; i < PC; ++i) mean += pk[i][t];
    mean *= (1.0f / (float)PC);
#pragma unroll
    for (int i = 0; i < PC; ++i) pk[i][t] -= mean;
    __syncthreads();
    int i = t >> 4, j = t & 15;
    float gg = 0.0f;
#pragma unroll 8
    for (int l = 0; l < 256; ++l) gg = fmaf(pk[i][l], pk[j][l], gg);
    gg -= (i == j) ? 1.0f : 0.0f;
    red[t] = gg * gg;
    __syncthreads();
    for (int s = 128; s; s >>= 1) { if (t < s) red[t] += red[t + s]; __syncthreads(); }
    if (t == 0) atomicAdd(ortho_out, sqrtf(red[0]) * (1.0f / 8.0f));
}

// ---------------------------------------------------------------------------
// Split-bf16 MFMA GEMM, BM=64 x BN=128, BK=64, 4 waves, SINGLE 48KB LDS buf,
// two-barrier loop: barrier -> ds_read all frags -> barrier -> stage(tk+1)
// -> 48 MFMAs.  8-chunk XOR swizzle (chunk+row)&7, <=2-way conflicts.
// MODE 0: relu -> split store
// MODE 3: tanh -> f32 store
// MODE 4: y<2 mu split store + |mu|^2 row-reduce; y>=2 logVar -> S row-reduce
// MODE 5: y<2 relu split store (dh); y==2 proto-distance epilogue + kl reduce
// ---------------------------------------------------------------------------
template<int MODE, int KK>
__global__ __launch_bounds__(256, 3)
void gemm_mfma(const u16* __restrict__ Ah_g, const u16* __restrict__ Al_g,
               const u16* __restrict__ Bh_g, const u16* __restrict__ Bl_g,
               const u16* __restrict__ Ph,   const u16* __restrict__ Pl,
               const float* __restrict__ bias,
               u16* __restrict__ Ch, u16* __restrict__ Cl,
               float* __restrict__ Cf,
               float* __restrict__ Srow, float* __restrict__ Mnorm,
               const int* __restrict__ tcls, const float* __restrict__ pnorm,
               const float* __restrict__ Wlast,
               float* __restrict__ out, float* __restrict__ kl_out,
               int ldc)
{
    __shared__ __align__(16) u16 LAh[64][64];
    __shared__ __align__(16) u16 LAl[64][64];
    __shared__ __align__(16) u16 LBh[128][64];
    __shared__ __align__(16) u16 LBl[128][64];
    __shared__ float klacc;

    const int t = threadIdx.x, lane = t & 63, wave = t >> 6;
    const int wm = wave >> 1, wn = wave & 1;
    const int bm = blockIdx.x * 64;
    const int y  = blockIdx.y;
    const bool proto = (MODE == 5) && (y == 2);
    const int bn = proto ? 0 : y * 128;
    const u16* Bh_p = proto ? Ph : Bh_g;
    const u16* Bl_p = proto ? Pl : Bl_g;
    const int rA = lane & 15, g = lane >> 4;
    const int wrow8 = lane >> 3, cp = lane & 7;   // staging: 8 rows x 8 chunks / GLD16

    if (t == 0) klacc = 0.f;

    f32x4 acc[2][4];
    const f32x4 z4 = {0.f, 0.f, 0.f, 0.f};
#pragma unroll
    for (int i = 0; i < 2; ++i)
#pragma unroll
        for (int j = 0; j < 4; ++j) acc[i][j] = z4;

    auto stage = [&](int kt) {   // 12 GLD16 per thread
#pragma unroll
        for (int s = 0; s < 2; ++s) {          // A: 2 slabs of 8 rows per wave
            int row = wave * 16 + s * 8 + wrow8;
            int c   = (cp - row) & 7;          // inverse swizzle on SOURCE
            size_t goff = (size_t)(bm + row) * KK + kt * 64 + c * 8;
            GLD16(Ah_g + goff, &LAh[wave * 16 + s * 8][0]);
            GLD16(Al_g + goff, &LAl[wave * 16 + s * 8][0]);
        }
#pragma unroll
        for (int s = 0; s < 4; ++s) {          // B: 4 slabs of 8 rows per wave
            int row = wave * 32 + s * 8 + wrow8;
            int c   = (cp - row) & 7;
            size_t goff = (size_t)(bn + row) * KK + kt * 64 + c * 8;
            GLD16(Bh_p + goff, &LBh[wave * 32 + s * 8][0]);
            GLD16(Bl_p + goff, &LBl[wave * 32 + s * 8][0]);
        }
    };

    constexpr int T = KK / 64;
    stage(0);
    for (int tk = 0; tk < T; ++tk) {
        __syncthreads();                 // vmcnt drained: tile tk in LDS

        bf16x8 aH[2][2], aL[2][2], bH[2][4], bL[2][4];   // [k-half][frag]
#pragma unroll
        for (int h = 0; h < 2; ++h) {
#pragma unroll
            for (int i = 0; i < 2; ++i) {
                int m = wm * 32 + i * 16 + rA;
                int c = ((h * 4 + g + m) & 7) * 8;        // swizzled READ
                aH[h][i] = *(const bf16x8*)&LAh[m][c];
                aL[h][i] = *(const bf16x8*)&LAl[m][c];
            }
#pragma unroll
            for (int j = 0; j < 4; ++j) {
                int n = wn * 64 + j * 16 + rA;
                int c = ((h * 4 + g + n) & 7) * 8;
                bH[h][j] = *(const bf16x8*)&LBh[n][c];
                bL[h][j] = *(const bf16x8*)&LBl[n][c];
            }
        }

        __syncthreads();                 // all reads done; safe to overwrite
        if (tk + 1 < T) stage(tk + 1);   // loads fly under the 48 MFMAs

#pragma unroll
        for (int h = 0; h < 2; ++h)
#pragma unroll
            for (int i = 0; i < 2; ++i)
#pragma unroll
                for (int j = 0; j < 4; ++j) {
                    acc[i][j] = __builtin_amdgcn_mfma_f32_16x16x32_bf16(aH[h][i], bH[h][j], acc[i][j], 0, 0, 0);
                    acc[i][j] = __builtin_amdgcn_mfma_f32_16x16x32_bf16(aL[h][i], bH[h][j], acc[i][j], 0, 0, 0);
                    acc[i][j] = __builtin_amdgcn_mfma_f32_16x16x32_bf16(aH[h][i], bL[h][j], acc[i][j], 0, 0, 0);
                }
    }

    if (proto) {
        // d^2 = |mu|^2 + |p|^2 - 2*cross for the class slab cols cls*16..+15
        float pn[4], wl[4];
#pragma unroll
        for (int j = 0; j < 4; ++j) {
            int col = wn * 64 + j * 16 + rA;
            pn[j] = pnorm[col];
            wl[j] = Wlast[col];
        }
#pragma unroll
        for (int i = 0; i < 2; ++i)
#pragma unroll
            for (int r = 0; r < 4; ++r) {
                int row = bm + wm * 32 + i * 16 + g * 4 + r;
                int cls = tcls[row];
                int jsel = cls & 3;
                bool owner = ((cls >> 2) == wn);
                float cv = 0.f, pnv = 0.f, wlv = 0.f;
#pragma unroll
                for (int j = 0; j < 4; ++j) {
                    bool sel = (j == jsel);
                    cv  = sel ? acc[i][j][r] : cv;
                    pnv = sel ? pn[j] : pnv;
                    wlv = sel ? wl[j] : wlv;
                }
                float dd  = fmaxf(Mnorm[row] + pnv - 2.f * cv, 0.f);
                float d   = sqrtf(dd);
                float sim = __logf((d + 1.0f) / (d + EPS_SIM));
                float kl  = Srow[row] + dd * (0.5f / 256.f);
                float klw = kl * sim;
                float num = klw;
                float den = (klw > 0.0f) ? sim : 0.0f;
                float ov  = sim * wlv;
                num += __shfl_xor(num, 1, 64); den += __shfl_xor(den, 1, 64); ov += __shfl_xor(ov, 1, 64);
                num += __shfl_xor(num, 2, 64); den += __shfl_xor(den, 2, 64); ov += __shfl_xor(ov, 2, 64);
                num += __shfl_xor(num, 4, 64); den += __shfl_xor(den, 4, 64); ov += __shfl_xor(ov, 4, 64);
                num += __shfl_xor(num, 8, 64); den += __shfl_xor(den, 8, 64); ov += __shfl_xor(ov, 8, 64);
                if (owner && rA == 0) {
                    out[row] = ov;
                    atomicAdd(&klacc, num / den);   // LDS atomic
                }
            }
        __syncthreads();
        if (t == 0) atomicAdd(kl_out, klacc * (1.f / (float)B_ROWS));
        return;
    }

    float bv[4];
#pragma unroll
    for (int j = 0; j < 4; ++j) bv[j] = bias[bn + wn * 64 + j * 16 + rA];

    if (MODE == 4 && y >= 2) {
        // logVar columns: S[row] += mean_l(0.5 e^lv - 0.5 lv - 0.5)
#pragma unroll
        for (int i = 0; i < 2; ++i)
#pragma unroll
            for (int r = 0; r < 4; ++r) {
                int row = bm + wm * 32 + i * 16 + g * 4 + r;
                float s = 0.f;
#pragma unroll
                for (int j = 0; j < 4; ++j) {
                    float lv = acc[i][j][r] + bv[j];
                    lv = fminf(fmaxf(lv, LOG_MIN_F), -LOG_MIN_F);
                    s += 0.5f * __expf(lv) - 0.5f * lv - 0.5f;
                }
                s += __shfl_xor(s, 1, 64); s += __shfl_xor(s, 2, 64);
                s += __shfl_xor(s, 4, 64); s += __shfl_xor(s, 8, 64);
                if (rA == 0) atomicAdd(&Srow[row], s * (1.f / 256.f));
            }
        return;
    }

#pragma unroll
    for (int i = 0; i < 2; ++i)
#pragma unroll
        for (int r = 0; r < 4; ++r) {
            size_t row = bm + wm * 32 + i * 16 + g * 4 + r;
            float sq = 0.f;
#pragma unroll
            for (int j = 0; j < 4; ++j) {
                int col = bn + wn * 64 + j * 16 + rA;
                float v = acc[i][j][r] + bv[j];
                if (MODE == 0 || MODE == 5) v = fmaxf(v, 0.f);
                if (MODE == 3) {
                    float e = __expf(2.f * v);
                    Cf[row * ldc + col] = 1.f - 2.f / (e + 1.f);
                } else {
                    u16 hh = f2bf(v);
                    u16 ll = f2bf(v - bf2f(hh));
                    Ch[row * ldc + col] = hh;
                    Cl[row * ldc + col] = ll;
                    if (MODE == 4) sq = fmaf(v, v, sq);
                }
            }
            if (MODE == 4) {   // |mu|^2 partial for this wave's 64 cols
                sq += __shfl_xor(sq, 1, 64); sq += __shfl_xor(sq, 2, 64);
                sq += __shfl_xor(sq, 4, 64); sq += __shfl_xor(sq, 8, 64);
                if (rA == 0) atomicAdd(&Mnorm[row], sq);
            }
        }
}

// ---------------------------------------------------------------------------
extern "C" void kernel_launch(void* const* d_in, const int* in_sizes, int n_in,
                              void* d_out, int out_size, void* d_ws, size_t ws_size,
                              hipStream_t stream)
{
    const float* x      = (const float*)d_in[0];
    const int*   tcls   = (const int*)  d_in[1];
    const float* protos = (const float*)d_in[2];
    const float* W1     = (const float*)d_in[3];
    const float* b1     = (const float*)d_in[4];
    const float* W2     = (const float*)d_in[5];
    const float* b2     = (const float*)d_in[6];
    const float* Wd1    = (const float*)d_in[7];
    const float* bd1    = (const float*)d_in[8];
    const float* Wd2    = (const float*)d_in[9];
    const float* bd2    = (const float*)d_in[10];
    const float* Wlast  = (const float*)d_in[11];

    float* out     = (float*)d_out;
    float* decoded = out + B_ROWS;

    // h (split bf16) lives in d_out's decoded region (33.55MB), overwritten by G4
    u16* h_h = (u16*)decoded;
    u16* h_l = h_h + 8388608;

    // workspace overlays: x region (32MB) reused for mu + dh after G1
    u16* wsu  = (u16*)d_ws;
    u16* x_h  = wsu;
    u16* x_l  = wsu + 8388608;
    u16* mu_h = wsu;
    u16* mu_l = wsu + 4194304;
    u16* dh_h = wsu + 8388608;
    u16* dh_l = wsu + 12582912;

    float* S     = (float*)((char*)d_ws + 33554432);
    float* klrow = S + 16384;                      // layout spacer
    u16* w = (u16*)(klrow + 16384);
    u16 *W1h = w, *W1l = w + 262144, *W2h = w + 524288, *W2l = w + 786432;
    u16 *Wd1h = w + 1048576, *Wd1l = w + 1114112, *Wd2h = w + 1179648, *Wd2l = w + 1310720;
    u16 *ph = w + 1441792, *pl = ph + 32768;       // protos split (128x256)
    float* munorm = (float*)(pl + 32768);          // 16384 f32
    float* pnorm  = munorm + 16384;                // 128 f32

    // prep: splits + pnorm + init (no LDS, pure streaming)
    hipLaunchKernelGGL(prep_kernel, dim3(8994), dim3(256), 0, stream,
                       x, W1, W2, Wd1, Wd2, protos,
                       x_h, x_l, W1h, W1l, W2h, W2l, Wd1h, Wd1l, Wd2h, Wd2l,
                       ph, pl, pnorm, S, munorm, out);
    // ortho loss: 8 parallel blocks (one per class)
    hipLaunchKernelGGL(ortho_kernel, dim3(8), dim3(256), 0, stream, protos, out + OR_IDX);

    // G1: h = relu(x @ W1^T + b1) -> split bf16
    hipLaunchKernelGGL((gemm_mfma<0, 512>), dim3(256, 4), dim3(256), 0, stream,
                       x_h, x_l, W1h, W1l, (u16*)nullptr, (u16*)nullptr, b1,
                       h_h, h_l, (float*)nullptr, (float*)nullptr, (float*)nullptr,
                       (int*)nullptr, (float*)nullptr, (float*)nullptr,
                       (float*)nullptr, (float*)nullptr, 512);
    // G2: conv = h @ W2^T + b2 -> mu split + munorm (y<2); S row-sums (y>=2)
    hipLaunchKernelGGL((gemm_mfma<4, 512>), dim3(256, 4), dim3(256), 0, stream,
                       h_h, h_l, W2h, W2l, (u16*)nullptr, (u16*)nullptr, b2,
                       mu_h, mu_l, (float*)nullptr, S, munorm,
                       (int*)nullptr, (float*)nullptr, (float*)nullptr,
                       (float*)nullptr, (float*)nullptr, 256);
    // G3': y<2: dh = relu(mu @ Wd1^T + bd1); y==2: proto distances + sim/kl/out
    hipLaunchKernelGGL((gemm_mfma<5, 256>), dim3(256, 3), dim3(256), 0, stream,
                       mu_h, mu_l, Wd1h, Wd1l, ph, pl, bd1,
                       dh_h, dh_l, (float*)nullptr, S, munorm,
                       tcls, pnorm, Wlast, out, out + KL_IDX, 256);
    // G4: decoded = tanh(dh @ Wd2^T + bd2) -> f32 (overwrites h region)
    hipLaunchKernelGGL((gemm_mfma<3, 256>), dim3(256, 4), dim3(256), 0, stream,
                       dh_h, dh_l, Wd2h, Wd2l, (u16*)nullptr, (u16*)nullptr, bd2,
                       (u16*)nullptr, (u16*)nullptr, decoded, (float*)nullptr, (float*)nullptr,
                       (int*)nullptr, (float*)nullptr, (float*)nullptr,
                       (float*)nullptr, (float*)nullptr, 512);
}